// Round 2
// baseline (2464.755 us; speedup 1.0000x reference)
//
#include <hip/hip_runtime.h>
#include <hip/hip_bf16.h>

// PicoLlmAttention fused pipeline, fp32 baseline.
// B=2, S=2048, E=1024, H=16, KV=4, D=64, window=1024 (read from device).
#define BB 2
#define SS 2048
#define EE 1024
#define NH 16
#define NKV 4
#define DD 64
#define RMS_EPS 1.1920929e-07f

// ---------------------------------------------------------------------------
// Kernel 1: fused QKV GEMM (+gate/ve for V, +RoPE/RMSNorm for Q,K)
// A = x [4096][1024], B = concat(Wq,Wk,Wv) rows, tile 128(M) x 64(N=1 head)
// grid (24, 32), block 256
// ---------------------------------------------------------------------------
__global__ __launch_bounds__(256)
void qkv_kernel(const float* __restrict__ x, const float* __restrict__ ve,
                const float* __restrict__ cosb, const float* __restrict__ sinb,
                const float* __restrict__ Wq, const float* __restrict__ Wk,
                const float* __restrict__ Wv, const float* __restrict__ Wg,
                float* __restrict__ qws, float* __restrict__ kws,
                float* __restrict__ vws)
{
    __shared__ float As[128 * 64];   // 32 KB, XOR-swizzled in k-blocks of 4
    __shared__ float Bs[64 * 64];    // 16 KB
    const int t  = threadIdx.x;
    const int ty = t >> 4, tx = t & 15;
    const int nt = blockIdx.x, mt = blockIdx.y;

    const float* W; int htype, head;
    if (nt < 16)      { W = Wq + (size_t)nt * 64 * EE;        htype = 0; head = nt; }
    else if (nt < 20) { W = Wk + (size_t)(nt - 16) * 64 * EE; htype = 1; head = nt - 16; }
    else              { W = Wv + (size_t)(nt - 20) * 64 * EE; htype = 2; head = nt - 20; }

    const float* Ab = x + (size_t)mt * 128 * EE;

    float acc[8][4];
#pragma unroll
    for (int i = 0; i < 8; i++)
#pragma unroll
        for (int j = 0; j < 4; j++) acc[i][j] = 0.f;

    for (int kt = 0; kt < EE; kt += 64) {
#pragma unroll
        for (int i = 0; i < 8; i++) {
            int row = i * 16 + ty;
            float4 v = *(const float4*)(Ab + (size_t)row * EE + kt + tx * 4);
            *(float4*)&As[row * 64 + ((tx ^ (row & 7)) << 2)] = v;
        }
#pragma unroll
        for (int i = 0; i < 4; i++) {
            int row = i * 16 + ty;
            float4 v = *(const float4*)(W + (size_t)row * EE + kt + tx * 4);
            *(float4*)&Bs[row * 64 + ((tx ^ (row & 7)) << 2)] = v;
        }
        __syncthreads();
#pragma unroll
        for (int k4 = 0; k4 < 16; k4++) {
            float4 b4[4];
#pragma unroll
            for (int j = 0; j < 4; j++) {
                int col = tx + 16 * j;
                b4[j] = *(const float4*)&Bs[col * 64 + ((k4 ^ (tx & 7)) << 2)];
            }
#pragma unroll
            for (int i = 0; i < 8; i++) {
                int row = ty + 16 * i;
                float4 a4 = *(const float4*)&As[row * 64 + ((k4 ^ (ty & 7)) << 2)];
#pragma unroll
                for (int j = 0; j < 4; j++) {
                    acc[i][j] += a4.x * b4[j].x + a4.y * b4[j].y
                               + a4.z * b4[j].z + a4.w * b4[j].w;
                }
            }
        }
        __syncthreads();
    }

    // ---- stash C tile into LDS (swizzled, stride 64) for epilogue ----
#pragma unroll
    for (int i = 0; i < 8; i++) {
        int row = ty + 16 * i;
#pragma unroll
        for (int j = 0; j < 4; j++) {
            int col = tx + 16 * j;
            As[row * 64 + (((col >> 2) ^ (row & 7)) << 2) + (col & 3)] = acc[i][j];
        }
    }
    __syncthreads();

    // ---- epilogue: 2 threads per row, each owns 32 consecutive d ----
    const int row  = t >> 1;
    const int p    = t & 1;
    const size_t grow = (size_t)mt * 128 + row;
    const int bb = (int)(grow >> 11);
    const int ss = (int)(grow & 2047);

    float vals[32];
#pragma unroll
    for (int c = 0; c < 8; c++) {
        int bk = (p * 8 + c) ^ (row & 7);
        float4 v = *(const float4*)&As[row * 64 + bk * 4];
        vals[c * 4 + 0] = v.x; vals[c * 4 + 1] = v.y;
        vals[c * 4 + 2] = v.z; vals[c * 4 + 3] = v.w;
    }

    if (htype < 2) {
        // RoPE + RMSNorm * 1.2
        float outv[32];
        float ssq = 0.f;
#pragma unroll
        for (int dd = 0; dd < 32; dd++) {
            float other = __shfl_xor(vals[dd], 1);   // partner half's value
            float cs = cosb[ss * 32 + dd];
            float sn = sinb[ss * 32 + dd];
            // p==0: out[d]    = t1*c + t2*s   (t1=own, t2=other)
            // p==1: out[d+32] = -t1*s + t2*c  (t1=other, t2=own)
            float o = (p == 0) ? (vals[dd] * cs + other * sn)
                               : (-other * sn + vals[dd] * cs);
            outv[dd] = o;
            ssq += o * o;
        }
        ssq += __shfl_xor(ssq, 1);
        float r = rsqrtf(ssq * (1.f / 64.f) + RMS_EPS) * 1.2f;
        float* dst = (htype == 0)
            ? (qws + (((size_t)bb * NH  + head) * SS + ss) * 64)
            : (kws + (((size_t)bb * NKV + head) * SS + ss) * 64);
        dst += p * 32;
#pragma unroll
        for (int c = 0; c < 8; c++) {
            float4 o4 = make_float4(outv[c*4]*r, outv[c*4+1]*r, outv[c*4+2]*r, outv[c*4+3]*r);
            *(float4*)(dst + c * 4) = o4;
        }
    } else {
        // V: add gate * ve
        float g = 0.f;
        const float* xr = x + grow * EE;
#pragma unroll
        for (int c = 0; c < 12; c++) g += xr[c] * Wg[head * 12 + c];
        g = 3.f / (1.f + __expf(-g));
        const float* ver = ve + grow * 256 + head * 64 + p * 32;
        float* dst = vws + (((size_t)bb * NKV + head) * SS + ss) * 64 + p * 32;
#pragma unroll
        for (int c = 0; c < 8; c++) {
            float4 vv = *(const float4*)(ver + c * 4);
            float4 o4 = make_float4(vals[c*4+0] + g*vv.x, vals[c*4+1] + g*vv.y,
                                    vals[c*4+2] + g*vv.z, vals[c*4+3] + g*vv.w);
            *(float4*)(dst + c * 4) = o4;
        }
    }
}

// ---------------------------------------------------------------------------
// Kernel 2: flash attention, 64-query tile per block, window + causal + mask
// grid (32 qtiles, 32 b*h), block 256
// ---------------------------------------------------------------------------
__global__ __launch_bounds__(256)
void attn_kernel(const float* __restrict__ qws, const float* __restrict__ kws,
                 const float* __restrict__ vws, const int* __restrict__ amask,
                 const int* __restrict__ lwp, float* __restrict__ yws)
{
    __shared__ float Qs[64 * 64];
    __shared__ float Ks[64 * 64];
    __shared__ float Vs[64 * 64];
    __shared__ float St[64 * 64];   // scores, stored transposed [k][q], swizzled
    const int t  = threadIdx.x;
    const int ty = t >> 4, tx = t & 15;
    const int qt = blockIdx.x, bh = blockIdx.y;
    const int b = bh >> 4, h = bh & 15, kvh = h >> 2;
    const int LW = lwp[0];
    const int q0 = qt * 64;

    const float* Qg = qws + (((size_t)b * NH  + h  ) * SS + q0) * 64;
    const float* Kg = kws + (((size_t)b * NKV + kvh) * SS      ) * 64;
    const float* Vg = vws + (((size_t)b * NKV + kvh) * SS      ) * 64;

#pragma unroll
    for (int i = 0; i < 4; i++) {
        int row = i * 16 + ty;
        float4 v = *(const float4*)(Qg + (size_t)row * 64 + tx * 4);
        *(float4*)&Qs[row * 64 + ((tx ^ (row & 7)) << 2)] = v;
    }

    // softmax-owner role: this thread owns row srow's m/l (replicated x4)
    const int srow = t >> 2, spart = t & 3;
    float m_reg = -1e30f, l_reg = 0.f;

    float acco[4][4];
#pragma unroll
    for (int i = 0; i < 4; i++)
#pragma unroll
        for (int j = 0; j < 4; j++) acco[i][j] = 0.f;

    int lo = q0 - LW + 1; if (lo < 0) lo = 0;
    const int kt_lo = lo >> 6;

    for (int kt = kt_lo; kt <= qt; kt++) {
        const int k0 = kt * 64;
        __syncthreads();   // previous iter's PV / loads done before overwrite
#pragma unroll
        for (int i = 0; i < 4; i++) {
            int row = i * 16 + ty;
            float4 kv = *(const float4*)(Kg + (size_t)(k0 + row) * 64 + tx * 4);
            *(float4*)&Ks[row * 64 + ((tx ^ (row & 7)) << 2)] = kv;
            float4 vv = *(const float4*)(Vg + (size_t)(k0 + row) * 64 + tx * 4);
            *(float4*)&Vs[row * 64 + ((tx ^ (row & 7)) << 2)] = vv;
        }
        __syncthreads();

        // ---- scores: S[4q x 4k] per thread ----
        float sacc[4][4];
#pragma unroll
        for (int i = 0; i < 4; i++)
#pragma unroll
            for (int j = 0; j < 4; j++) sacc[i][j] = 0.f;
#pragma unroll
        for (int k4 = 0; k4 < 16; k4++) {
            float4 b4[4];
#pragma unroll
            for (int j = 0; j < 4; j++) {
                int col = tx + 16 * j;
                b4[j] = *(const float4*)&Ks[col * 64 + ((k4 ^ (tx & 7)) << 2)];
            }
#pragma unroll
            for (int i = 0; i < 4; i++) {
                int row = 4 * ty + i;
                float4 a4 = *(const float4*)&Qs[row * 64 + ((k4 ^ (row & 7)) << 2)];
#pragma unroll
                for (int j = 0; j < 4; j++) {
                    sacc[i][j] += a4.x * b4[j].x + a4.y * b4[j].y
                                + a4.z * b4[j].z + a4.w * b4[j].w;
                }
            }
        }
        // ---- mask + store transposed to St ----
#pragma unroll
        for (int i = 0; i < 4; i++) {
            int qg = q0 + 4 * ty + i;
#pragma unroll
            for (int j = 0; j < 4; j++) {
                int col = tx + 16 * j;
                int kg  = k0 + col;
                float sc = sacc[i][j] * 0.125f;
                bool ok = (kg <= qg) && (qg - kg < LW) && (amask[(b << 11) + kg] != 0);
                St[col * 64 + ((ty ^ (col & 7)) << 2) + i] = ok ? sc : -3.0e38f;
            }
        }
        __syncthreads();

        // ---- online softmax on St columns (per q row) ----
        float mx = -3.0e38f;
#pragma unroll
        for (int kk = 0; kk < 16; kk++) {
            int k = spart * 16 + kk;
            mx = fmaxf(mx, St[k * 64 + (((srow >> 2) ^ (k & 7)) << 2) + (srow & 3)]);
        }
        mx = fmaxf(mx, __shfl_xor(mx, 1));
        mx = fmaxf(mx, __shfl_xor(mx, 2));
        float mnew = fmaxf(m_reg, mx);
        float al   = __expf(m_reg - mnew);
        float sum  = 0.f;
#pragma unroll
        for (int kk = 0; kk < 16; kk++) {
            int k = spart * 16 + kk;
            int idx = k * 64 + (((srow >> 2) ^ (k & 7)) << 2) + (srow & 3);
            float pp = __expf(St[idx] - mnew);
            St[idx] = pp;
            sum += pp;
        }
        sum += __shfl_xor(sum, 1);
        sum += __shfl_xor(sum, 2);
        m_reg = mnew;
        l_reg = l_reg * al + sum;
        __syncthreads();

        // ---- PV: O[4q x 4d] += P^T x V ----
        float alph[4];
#pragma unroll
        for (int i = 0; i < 4; i++) {
            int lane = ((4 * ty + i) & 15) * 4;  // owner lane of that row in this wave
            alph[i] = __shfl(al, lane);
        }
#pragma unroll
        for (int i = 0; i < 4; i++)
#pragma unroll
            for (int j = 0; j < 4; j++) acco[i][j] *= alph[i];
#pragma unroll
        for (int k = 0; k < 64; k++) {
            float4 p4 = *(const float4*)&St[k * 64 + ((ty ^ (k & 7)) << 2)];
            float4 v4 = *(const float4*)&Vs[k * 64 + ((tx ^ (k & 7)) << 2)];
            acco[0][0] += p4.x * v4.x; acco[0][1] += p4.x * v4.y;
            acco[0][2] += p4.x * v4.z; acco[0][3] += p4.x * v4.w;
            acco[1][0] += p4.y * v4.x; acco[1][1] += p4.y * v4.y;
            acco[1][2] += p4.y * v4.z; acco[1][3] += p4.y * v4.w;
            acco[2][0] += p4.z * v4.x; acco[2][1] += p4.z * v4.y;
            acco[2][2] += p4.z * v4.z; acco[2][3] += p4.z * v4.w;
            acco[3][0] += p4.w * v4.x; acco[3][1] += p4.w * v4.y;
            acco[3][2] += p4.w * v4.z; acco[3][3] += p4.w * v4.w;
        }
    }

    // ---- finalize: divide by l, write y in [b][s][h*64+d] ----
#pragma unroll
    for (int i = 0; i < 4; i++) {
        int q = 4 * ty + i;
        float li = __shfl(l_reg, (q & 15) * 4);
        float inv = 1.f / li;
        float4 o = make_float4(acco[i][0] * inv, acco[i][1] * inv,
                               acco[i][2] * inv, acco[i][3] * inv);
        *(float4*)(yws + ((size_t)(b << 11) + q0 + q) * EE + h * 64 + tx * 4) = o;
    }
}

// ---------------------------------------------------------------------------
// Kernel 3: output projection  out[4096][1024] = y @ Wproj^T
// grid (16, 32), block 256
// ---------------------------------------------------------------------------
__global__ __launch_bounds__(256)
void proj_kernel(const float* __restrict__ A, const float* __restrict__ W,
                 float* __restrict__ out)
{
    __shared__ float As[128 * 64];
    __shared__ float Bs[64 * 64];
    const int t  = threadIdx.x;
    const int ty = t >> 4, tx = t & 15;
    const int nt = blockIdx.x, mt = blockIdx.y;

    const float* Ab = A + (size_t)mt * 128 * EE;
    const float* Wb = W + (size_t)nt * 64 * EE;

    float acc[8][4];
#pragma unroll
    for (int i = 0; i < 8; i++)
#pragma unroll
        for (int j = 0; j < 4; j++) acc[i][j] = 0.f;

    for (int kt = 0; kt < EE; kt += 64) {
#pragma unroll
        for (int i = 0; i < 8; i++) {
            int row = i * 16 + ty;
            float4 v = *(const float4*)(Ab + (size_t)row * EE + kt + tx * 4);
            *(float4*)&As[row * 64 + ((tx ^ (row & 7)) << 2)] = v;
        }
#pragma unroll
        for (int i = 0; i < 4; i++) {
            int row = i * 16 + ty;
            float4 v = *(const float4*)(Wb + (size_t)row * EE + kt + tx * 4);
            *(float4*)&Bs[row * 64 + ((tx ^ (row & 7)) << 2)] = v;
        }
        __syncthreads();
#pragma unroll
        for (int k4 = 0; k4 < 16; k4++) {
            float4 b4[4];
#pragma unroll
            for (int j = 0; j < 4; j++) {
                int col = tx + 16 * j;
                b4[j] = *(const float4*)&Bs[col * 64 + ((k4 ^ (tx & 7)) << 2)];
            }
#pragma unroll
            for (int i = 0; i < 8; i++) {
                int row = ty + 16 * i;
                float4 a4 = *(const float4*)&As[row * 64 + ((k4 ^ (ty & 7)) << 2)];
#pragma unroll
                for (int j = 0; j < 4; j++) {
                    acc[i][j] += a4.x * b4[j].x + a4.y * b4[j].y
                               + a4.z * b4[j].z + a4.w * b4[j].w;
                }
            }
        }
        __syncthreads();
    }

    // ---- re-stage C through LDS for vectorized coalesced store ----
#pragma unroll
    for (int i = 0; i < 8; i++) {
        int row = ty + 16 * i;
#pragma unroll
        for (int j = 0; j < 4; j++) {
            int col = tx + 16 * j;
            As[row * 64 + (((col >> 2) ^ (row & 7)) << 2) + (col & 3)] = acc[i][j];
        }
    }
    __syncthreads();

    const int row = t >> 1;
    const int p   = t & 1;
    const size_t grow = (size_t)mt * 128 + row;
    float* dst = out + grow * EE + nt * 64 + p * 32;
#pragma unroll
    for (int c = 0; c < 8; c++) {
        int bk = (p * 8 + c) ^ (row & 7);
        float4 v = *(const float4*)&As[row * 64 + bk * 4];
        *(float4*)(dst + c * 4) = v;
    }
}

// ---------------------------------------------------------------------------
extern "C" void kernel_launch(void* const* d_in, const int* in_sizes, int n_in,
                              void* d_out, int out_size, void* d_ws, size_t ws_size,
                              hipStream_t stream)
{
    (void)in_sizes; (void)n_in; (void)out_size; (void)ws_size;
    const float* x     = (const float*)d_in[0];
    const float* ve    = (const float*)d_in[1];
    const float* cosb  = (const float*)d_in[2];
    const float* sinb  = (const float*)d_in[3];
    const float* Wq    = (const float*)d_in[4];
    const float* Wk    = (const float*)d_in[5];
    const float* Wv    = (const float*)d_in[6];
    const float* Wp    = (const float*)d_in[7];
    const float* Wg    = (const float*)d_in[8];
    const int*   amask = (const int*)d_in[9];
    const int*   lw    = (const int*)d_in[10];
    float* out = (float*)d_out;

    float* ws  = (float*)d_ws;
    float* qws = ws;                 // 2*16*2048*64 = 4,194,304 floats
    float* kws = ws + 4194304;       // 1,048,576
    float* vws = ws + 5242880;       // 1,048,576
    float* yws = ws + 6291456;       // 4,194,304  (total 40 MB)

    qkv_kernel<<<dim3(24, 32), 256, 0, stream>>>(x, ve, cosb, sinb, Wq, Wk, Wv, Wg,
                                                 qws, kws, vws);
    attn_kernel<<<dim3(32, 32), 256, 0, stream>>>(qws, kws, vws, amask, lw, yws);
    proj_kernel<<<dim3(16, 32), 256, 0, stream>>>(yws, Wp, out);
}

// Round 6
// 424.565 us; speedup vs baseline: 5.8054x; 5.8054x over previous
//
#include <hip/hip_runtime.h>
#include <hip/hip_bf16.h>

// PicoLlmAttention: split-bf16 (hi+lo) MFMA pipeline, fp32-accurate everywhere.
// B=2, S=2048, E=1024, H=16, KV=4, D=64, window read from device.
#define SS 2048
#define EE 1024
#define RMS_EPS 1.1920929e-07f

typedef short v8s __attribute__((ext_vector_type(8)));   // 8 bf16 (4 VGPR)
typedef float v4f __attribute__((ext_vector_type(4)));   // MFMA acc

#define MFMA16 __builtin_amdgcn_mfma_f32_16x16x32_bf16

__device__ __forceinline__ ushort f2bf(float f){
    union { __hip_bfloat16 b; ushort u; } c; c.b = __float2bfloat16(f); return c.u;
}
__device__ __forceinline__ float bf2f(ushort u){
    union { uint u; float f; } c; c.u = ((uint)u) << 16; return c.f;
}
// split 8 consecutive fp32 into hi/lo bf16 packs (hi+lo ~ 16+ mantissa bits)
__device__ __forceinline__ void split8(const float* p, uint4& H, uint4& L){
    float4 a = *(const float4*)p, b = *(const float4*)(p+4);
    float v[8] = {a.x,a.y,a.z,a.w,b.x,b.y,b.z,b.w};
    ushort hs[8], ls[8];
#pragma unroll
    for (int e=0;e<8;e++){
        ushort h = f2bf(v[e]);
        hs[e] = h;
        ls[e] = f2bf(v[e] - bf2f(h));
    }
    H = *(uint4*)hs; L = *(uint4*)ls;
}

// ---------------------------------------------------------------------------
// Q/K projection: split-bf16 MFMA GEMM 128(M s) x 64(N d, one head),
// fused RoPE + RMSNorm*1.2, outputs q,k as hi/lo bf16 pairs.
// grid (20, 32), block 256 (4 waves; wave w owns 32 M-rows)
// ---------------------------------------------------------------------------
__global__ __launch_bounds__(256)
void qk_kernel(const float* __restrict__ x, const float* __restrict__ Wq,
               const float* __restrict__ Wk, const float* __restrict__ cosb,
               const float* __restrict__ sinb,
               ushort* __restrict__ qhb, ushort* __restrict__ qlb,
               ushort* __restrict__ khb, ushort* __restrict__ klb)
{
    __shared__ ushort Axh[128*64];   // 16 KB
    __shared__ ushort Axl[128*64];   // 16 KB
    __shared__ ushort Bwh[64*64];    //  8 KB
    __shared__ ushort Bwl[64*64];    //  8 KB
    const int t = threadIdx.x;
    const int lane = t & 63, w = t >> 6;
    const int g = lane >> 4, ln = lane & 15;
    const int nt = blockIdx.x, mt = blockIdx.y;
    const float* W = (nt < 16) ? (Wq + (size_t)nt*64*EE)
                               : (Wk + (size_t)(nt-16)*64*EE);
    const v4f vzero = {0.f,0.f,0.f,0.f};
    v4f acc[2][4];
#pragma unroll
    for (int m=0;m<2;m++)
#pragma unroll
        for (int j=0;j<4;j++) acc[m][j] = vzero;

    const int sr = t>>3, sc = t&7;
    for (int kt = 0; kt < EE; kt += 64){
#pragma unroll
        for (int p2=0;p2<4;p2++){
            int rr = sr + 32*p2;
            uint4 H,L; split8(x + (size_t)(mt*128+rr)*EE + kt + sc*8, H, L);
            int off = rr*64 + ((sc ^ (rr&7))<<3);
            *(uint4*)&Axh[off] = H; *(uint4*)&Axl[off] = L;
        }
#pragma unroll
        for (int p2=0;p2<2;p2++){
            int rr = sr + 32*p2;
            uint4 H,L; split8(W + (size_t)rr*EE + kt + sc*8, H, L);
            int off = rr*64 + ((sc ^ (rr&7))<<3);
            *(uint4*)&Bwh[off] = H; *(uint4*)&Bwl[off] = L;
        }
        __syncthreads();
        v8s ah[2][2], al[2][2], bh[4][2], bl[4][2];
#pragma unroll
        for (int m=0;m<2;m++){
            int row = 32*w + 16*m + ln;
#pragma unroll
            for (int s=0;s<2;s++){
                int off = row*64 + (((4*s+g) ^ (row&7))<<3);
                ah[m][s] = *(v8s*)&Axh[off];
                al[m][s] = *(v8s*)&Axl[off];
            }
        }
#pragma unroll
        for (int j=0;j<4;j++){
            int row = 16*j + ln;
#pragma unroll
            for (int s=0;s<2;s++){
                int off = row*64 + (((4*s+g) ^ (row&7))<<3);
                bh[j][s] = *(v8s*)&Bwh[off];
                bl[j][s] = *(v8s*)&Bwl[off];
            }
        }
#pragma unroll
        for (int m=0;m<2;m++)
#pragma unroll
            for (int j=0;j<4;j++)
#pragma unroll
                for (int s=0;s<2;s++){
                    acc[m][j] = MFMA16(ah[m][s], bh[j][s], acc[m][j], 0,0,0);
                    acc[m][j] = MFMA16(ah[m][s], bl[j][s], acc[m][j], 0,0,0);
                    acc[m][j] = MFMA16(al[m][s], bh[j][s], acc[m][j], 0,0,0);
                }
        __syncthreads();
    }

    // epilogue: lane holds C cols d = {ln, 16+ln, 32+ln, 48+ln}, rows s = 32w+16m+4g+r
    const int bb = (mt*128) >> 11;
#pragma unroll
    for (int m=0;m<2;m++){
#pragma unroll
        for (int r=0;r<4;r++){
            int srow = mt*128 + 32*w + 16*m + 4*g + r;
            int ss_ = srow & 2047;
            float v0 = acc[m][0][r], v1 = acc[m][1][r];
            float v2 = acc[m][2][r], v3 = acc[m][3][r];
            float c0 = cosb[ss_*32 + ln],      s0 = sinb[ss_*32 + ln];
            float c1 = cosb[ss_*32 + 16 + ln], s1 = sinb[ss_*32 + 16 + ln];
            float lo0 =  v0*c0 + v2*s0, hi0 = -v0*s0 + v2*c0;  // d=ln    / d=32+ln
            float lo1 =  v1*c1 + v3*s1, hi1 = -v1*s1 + v3*c1;  // d=16+ln / d=48+ln
            float ssq = lo0*lo0 + hi0*hi0 + lo1*lo1 + hi1*hi1;
            ssq += __shfl_xor(ssq, 1); ssq += __shfl_xor(ssq, 2);
            ssq += __shfl_xor(ssq, 4); ssq += __shfl_xor(ssq, 8);
            float rs = rsqrtf(ssq*(1.f/64.f) + RMS_EPS) * 1.2f;
            size_t base = (nt < 16) ? ((size_t)(bb*16 + nt)*SS + ss_)*64
                                    : ((size_t)(bb*4 + (nt-16))*SS + ss_)*64;
            ushort* dh = (nt < 16) ? (qhb + base) : (khb + base);
            ushort* dl = (nt < 16) ? (qlb + base) : (klb + base);
            float o0 = lo0*rs, o1 = lo1*rs, o2 = hi0*rs, o3 = hi1*rs;
            ushort h0 = f2bf(o0), h1 = f2bf(o1), h2 = f2bf(o2), h3 = f2bf(o3);
            dh[ln]    = h0; dl[ln]    = f2bf(o0 - bf2f(h0));
            dh[16+ln] = h1; dl[16+ln] = f2bf(o1 - bf2f(h1));
            dh[32+ln] = h2; dl[32+ln] = f2bf(o2 - bf2f(h2));
            dh[48+ln] = h3; dl[48+ln] = f2bf(o3 - bf2f(h3));
        }
    }
}

// ---------------------------------------------------------------------------
// V projection: fp32 vector GEMM + gate*ve, writes split-bf16 V^T (hi/lo)
// v layout: [b*4+kvh][64 d][2048 s].  grid (4, 32), block 256
// ---------------------------------------------------------------------------
__global__ __launch_bounds__(256)
void v_kernel(const float* __restrict__ x, const float* __restrict__ ve,
              const float* __restrict__ Wv, const float* __restrict__ Wg,
              ushort* __restrict__ vhT, ushort* __restrict__ vlT)
{
    __shared__ float As[128 * 64];
    __shared__ float Bs[64 * 64];
    const int t  = threadIdx.x;
    const int ty = t >> 4, tx = t & 15;
    const int nt = blockIdx.x, mt = blockIdx.y;
    const float* W  = Wv + (size_t)nt * 64 * EE;
    const float* Ab = x + (size_t)mt * 128 * EE;

    float acc[8][4];
#pragma unroll
    for (int i = 0; i < 8; i++)
#pragma unroll
        for (int j = 0; j < 4; j++) acc[i][j] = 0.f;

    for (int kt = 0; kt < EE; kt += 64) {
#pragma unroll
        for (int i = 0; i < 8; i++) {
            int row = i * 16 + ty;
            float4 v = *(const float4*)(Ab + (size_t)row * EE + kt + tx * 4);
            *(float4*)&As[row * 64 + ((tx ^ (row & 7)) << 2)] = v;
        }
#pragma unroll
        for (int i = 0; i < 4; i++) {
            int row = i * 16 + ty;
            float4 v = *(const float4*)(W + (size_t)row * EE + kt + tx * 4);
            *(float4*)&Bs[row * 64 + ((tx ^ (row & 7)) << 2)] = v;
        }
        __syncthreads();
#pragma unroll
        for (int k4 = 0; k4 < 16; k4++) {
            float4 b4[4];
#pragma unroll
            for (int j = 0; j < 4; j++) {
                int col = tx + 16 * j;
                b4[j] = *(const float4*)&Bs[col * 64 + ((k4 ^ (tx & 7)) << 2)];
            }
#pragma unroll
            for (int i = 0; i < 8; i++) {
                int row = ty + 16 * i;
                float4 a4 = *(const float4*)&As[row * 64 + ((k4 ^ (ty & 7)) << 2)];
#pragma unroll
                for (int j = 0; j < 4; j++) {
                    acc[i][j] += a4.x * b4[j].x + a4.y * b4[j].y
                               + a4.z * b4[j].z + a4.w * b4[j].w;
                }
            }
        }
        __syncthreads();
    }

    // restage C to LDS, then epilogue: 2 threads/row
#pragma unroll
    for (int i = 0; i < 8; i++) {
        int row = ty + 16 * i;
#pragma unroll
        for (int j = 0; j < 4; j++) {
            int col = tx + 16 * j;
            As[row * 64 + (((col >> 2) ^ (row & 7)) << 2) + (col & 3)] = acc[i][j];
        }
    }
    __syncthreads();

    const int row = t >> 1, p = t & 1;
    const size_t grow = (size_t)mt * 128 + row;
    const int bb = (int)(grow >> 11);
    const int ss_ = (int)(grow & 2047);

    float gte = 0.f;
    const float* xr = x + grow * EE;
#pragma unroll
    for (int c = 0; c < 12; c++) gte += xr[c] * Wg[nt * 12 + c];
    gte = 3.f / (1.f + __expf(-gte));
    const float* ver = ve + grow * 256 + nt * 64 + p * 32;
    ushort* vhd = vhT + (size_t)(bb*4 + nt)*64*SS + ss_;
    ushort* vld = vlT + (size_t)(bb*4 + nt)*64*SS + ss_;
#pragma unroll
    for (int c = 0; c < 8; c++) {
        int bk = (p * 8 + c) ^ (row & 7);
        float4 v = *(const float4*)&As[row * 64 + bk * 4];
        float4 vv = *(const float4*)(ver + c * 4);
        float ov[4] = {v.x + gte*vv.x, v.y + gte*vv.y, v.z + gte*vv.z, v.w + gte*vv.w};
        int d0 = p*32 + 4*c;
#pragma unroll
        for (int j = 0; j < 4; j++){
            ushort h = f2bf(ov[j]);
            vhd[(size_t)(d0+j)*SS] = h;
            vld[(size_t)(d0+j)*SS] = f2bf(ov[j] - bf2f(h));
        }
    }
}

// ---------------------------------------------------------------------------
// Flash attention, split-bf16 QK^T and PV (3-term each); P stays in registers.
// grid (32 qtiles, 32 b*h), block 256 (4 waves; wave w owns q rows 16w..16w+15)
// ---------------------------------------------------------------------------
__global__ __launch_bounds__(256)
void attn_kernel(const ushort* __restrict__ qhb, const ushort* __restrict__ qlb,
                 const ushort* __restrict__ khb, const ushort* __restrict__ klb,
                 const ushort* __restrict__ vhT, const ushort* __restrict__ vlT,
                 const int* __restrict__ amask, const int* __restrict__ lwp,
                 ushort* __restrict__ yhb, ushort* __restrict__ ylb)
{
    __shared__ ushort SMEM[24576];   // Qh|Ql|Kh|Kl|Vh|Vl (4096 ush each); epi: Ot f32
    __shared__ float mbias[64];
    ushort* Qh = SMEM;
    ushort* Ql = SMEM + 4096;
    ushort* Kh = SMEM + 8192;
    ushort* Kl = SMEM + 12288;
    ushort* Vh = SMEM + 16384;
    ushort* Vl = SMEM + 20480;
    const int t = threadIdx.x, lane = t & 63, w = t >> 6;
    const int g = lane >> 4, ln = lane & 15;
    const int qt = blockIdx.x, bh = blockIdx.y;
    const int b = bh >> 4, h = bh & 15, kvh = h >> 2;
    const int LW = lwp[0];
    const int q0 = qt*64;
    const ushort* Qhp = qhb + ((size_t)(b*16+h)*SS + q0)*64;
    const ushort* Qlp = qlb + ((size_t)(b*16+h)*SS + q0)*64;
    const ushort* Khp = khb + ((size_t)(b*4+kvh)*SS)*64;
    const ushort* Klp = klb + ((size_t)(b*4+kvh)*SS)*64;
    const ushort* Vhp = vhT + (size_t)(b*4+kvh)*64*SS;
    const ushort* Vlp = vlT + (size_t)(b*4+kvh)*64*SS;

    const int sr = t>>3, sc = t&7;
#pragma unroll
    for (int p2=0;p2<2;p2++){
        int rr = sr + 32*p2;
        int off = rr*64 + ((sc ^ (rr&7))<<3);
        *(uint4*)&Qh[off] = *(const uint4*)(Qhp + (size_t)rr*64 + sc*8);
        *(uint4*)&Ql[off] = *(const uint4*)(Qlp + (size_t)rr*64 + sc*8);
    }
    __syncthreads();
    v8s qfh[2], qfl[2];
    {
        int row = 16*w + ln;
#pragma unroll
        for (int s=0;s<2;s++){
            int off = row*64 + (((4*s+g) ^ (row&7))<<3);
            qfh[s] = *(v8s*)&Qh[off];
            qfl[s] = *(v8s*)&Ql[off];
        }
    }
    const int qg = q0 + 16*w + ln;
    const int keyk = (ln&3) ^ ((ln>>2)<<1);
    float m_r = -1e30f, l_r = 0.f;
    const v4f vzero = {0.f,0.f,0.f,0.f};
    v4f o[4];
#pragma unroll
    for (int dt=0;dt<4;dt++) o[dt] = vzero;

    int lo = q0 - LW + 1; if (lo < 0) lo = 0;
    for (int kt = lo>>6; kt <= qt; kt++){
        int k0 = kt*64;
        __syncthreads();
#pragma unroll
        for (int p2=0;p2<2;p2++){
            int rr = sr + 32*p2;
            int kkey = (rr&3) ^ (((rr>>3)&3)<<1);
            int koff = rr*64 + ((sc ^ kkey)<<3);
            *(uint4*)&Kh[koff] = *(const uint4*)(Khp + (size_t)(k0+rr)*64 + sc*8);
            *(uint4*)&Kl[koff] = *(const uint4*)(Klp + (size_t)(k0+rr)*64 + sc*8);
            int voff = rr*64 + ((sc ^ (rr&7))<<3);
            *(uint4*)&Vh[voff] = *(const uint4*)(Vhp + (size_t)rr*SS + k0 + sc*8);
            *(uint4*)&Vl[voff] = *(const uint4*)(Vlp + (size_t)rr*SS + k0 + sc*8);
        }
        if (t < 64) mbias[t] = amask[(b<<11) + k0 + t] ? 0.f : -3.0e38f;
        __syncthreads();

        // S^T = K . Q^T (3-term split), permuted k-rows
        float p[4][4];
#pragma unroll
        for (int tau=0;tau<4;tau++){
            v4f sa = vzero;
            int krow = 32*(tau&1) + 8*(ln>>2) + 4*(tau>>1) + (ln&3);
#pragma unroll
            for (int s=0;s<2;s++){
                int off = krow*64 + (((4*s+g) ^ keyk)<<3);
                v8s afh = *(v8s*)&Kh[off];
                v8s afl = *(v8s*)&Kl[off];
                sa = MFMA16(afh, qfh[s], sa, 0,0,0);
                sa = MFMA16(afh, qfl[s], sa, 0,0,0);
                sa = MFMA16(afl, qfh[s], sa, 0,0,0);
            }
#pragma unroll
            for (int r=0;r<4;r++) p[tau][r] = sa[r];
        }

        // mask + online softmax (per-lane: col q = ln is this lane's q)
        float pmax = -3.0e38f;
#pragma unroll
        for (int tau=0;tau<4;tau++)
#pragma unroll
            for (int r=0;r<4;r++){
                int kk  = 32*(tau&1) + 8*g + 4*(tau>>1) + r;
                int kgl = k0 + kk;
                float scv = p[tau][r]*0.125f + mbias[kk];
                bool ok = (kgl <= qg) && (qg - kgl < LW);
                scv = ok ? scv : -3.0e38f;
                p[tau][r] = scv;
                pmax = fmaxf(pmax, scv);
            }
        pmax = fmaxf(pmax, __shfl_xor(pmax,16));
        pmax = fmaxf(pmax, __shfl_xor(pmax,32));
        float mnew = fmaxf(m_r, pmax);
        float al = __expf(m_r - mnew);
        float ls = 0.f;
#pragma unroll
        for (int tau=0;tau<4;tau++)
#pragma unroll
            for (int r=0;r<4;r++){
                float e = __expf(p[tau][r] - mnew);
                p[tau][r] = e; ls += e;
            }
        ls += __shfl_xor(ls,16); ls += __shfl_xor(ls,32);
        m_r = mnew; l_r = l_r*al + ls;

        // pack split P (per-lane): B-frag elem e of K-step s <- p[2*(e>>2)+s][e&3]
        v8s pbh[2], pbl[2];
#pragma unroll
        for (int s=0;s<2;s++){
            v8s ph, pl;
#pragma unroll
            for (int e=0;e<8;e++){
                float val = p[2*(e>>2)+s][e&3];
                ushort hh = f2bf(val);
                ph[e] = (short)hh;
                pl[e] = (short)f2bf(val - bf2f(hh));
            }
            pbh[s]=ph; pbl[s]=pl;
        }
        // O^T += V^T . P^T (3-term split)
#pragma unroll
        for (int dt=0;dt<4;dt++){
            o[dt] = o[dt]*al;
            int drow = 16*dt + ln;
#pragma unroll
            for (int s=0;s<2;s++){
                int off = drow*64 + (((4*s+g) ^ (ln&7))<<3);
                v8s vfh = *(v8s*)&Vh[off];
                v8s vfl = *(v8s*)&Vl[off];
                o[dt] = MFMA16(vfh, pbh[s], o[dt], 0,0,0);
                o[dt] = MFMA16(vfh, pbl[s], o[dt], 0,0,0);
                o[dt] = MFMA16(vfl, pbh[s], o[dt], 0,0,0);
            }
        }
    }

    // epilogue: O^T -> LDS transpose (stride 68) -> coalesced split-bf16 y rows
    __syncthreads();
    float inv = (l_r > 0.f) ? (1.0f / l_r) : 0.f;
    float* Ot = (float*)SMEM;
#pragma unroll
    for (int dt=0;dt<4;dt++)
#pragma unroll
        for (int r=0;r<4;r++){
            int d = 16*dt + 4*g + r;
            Ot[d*68 + 16*w + ln] = o[dt][r]*inv;
        }
    __syncthreads();
    {
        int q = t>>2, dp = t&3;
        ushort th[16], tl[16];
#pragma unroll
        for (int i=0;i<16;i++){
            float val = Ot[(dp*16+i)*68 + q];
            ushort hh = f2bf(val);
            th[i] = hh;
            tl[i] = f2bf(val - bf2f(hh));
        }
        size_t doff = (size_t)(b*SS + q0 + q)*EE + h*64 + dp*16;
        *(uint4*)(yhb + doff)     = *(uint4*)&th[0];
        *(uint4*)(yhb + doff + 8) = *(uint4*)&th[8];
        *(uint4*)(ylb + doff)     = *(uint4*)&tl[0];
        *(uint4*)(ylb + doff + 8) = *(uint4*)&tl[8];
    }
}

// ---------------------------------------------------------------------------
// Output projection: split-bf16 MFMA GEMM (y hi/lo from ws, Wp split in staging),
// out fp32.  grid (16, 32), block 256
// ---------------------------------------------------------------------------
__global__ __launch_bounds__(256)
void proj_kernel(const ushort* __restrict__ yhb, const ushort* __restrict__ ylb,
                 const float* __restrict__ Wp, float* __restrict__ out)
{
    __shared__ ushort Ayh[128*64];   // 16 KB
    __shared__ ushort Ayl[128*64];   // 16 KB
    __shared__ ushort Bh[64*64];     //  8 KB
    __shared__ ushort Bl[64*64];     //  8 KB
    const int t = threadIdx.x;
    const int lane = t & 63, w = t >> 6;
    const int g = lane >> 4, ln = lane & 15;
    const int nt = blockIdx.x, mt = blockIdx.y;
    const v4f vzero = {0.f,0.f,0.f,0.f};
    v4f acc[2][4];
#pragma unroll
    for (int m=0;m<2;m++)
#pragma unroll
        for (int j=0;j<4;j++) acc[m][j] = vzero;

    const int sr = t>>3, sc = t&7;
    for (int kt = 0; kt < EE; kt += 64){
#pragma unroll
        for (int p2=0;p2<4;p2++){
            int rr = sr + 32*p2;
            int off = rr*64 + ((sc ^ (rr&7))<<3);
            *(uint4*)&Ayh[off] = *(const uint4*)(yhb + (size_t)(mt*128+rr)*EE + kt + sc*8);
            *(uint4*)&Ayl[off] = *(const uint4*)(ylb + (size_t)(mt*128+rr)*EE + kt + sc*8);
        }
#pragma unroll
        for (int p2=0;p2<2;p2++){
            int rr = sr + 32*p2;
            uint4 H,L; split8(Wp + (size_t)(nt*64+rr)*EE + kt + sc*8, H, L);
            int off = rr*64 + ((sc ^ (rr&7))<<3);
            *(uint4*)&Bh[off] = H; *(uint4*)&Bl[off] = L;
        }
        __syncthreads();
        v8s ah[2][2], al[2][2], bh[4][2], bl[4][2];
#pragma unroll
        for (int m=0;m<2;m++){
            int row = 32*w + 16*m + ln;
#pragma unroll
            for (int s=0;s<2;s++){
                int off = row*64 + (((4*s+g) ^ (row&7))<<3);
                ah[m][s] = *(v8s*)&Ayh[off];
                al[m][s] = *(v8s*)&Ayl[off];
            }
        }
#pragma unroll
        for (int j=0;j<4;j++){
            int row = 16*j + ln;
#pragma unroll
            for (int s=0;s<2;s++){
                int off = row*64 + (((4*s+g) ^ (row&7))<<3);
                bh[j][s] = *(v8s*)&Bh[off];
                bl[j][s] = *(v8s*)&Bl[off];
            }
        }
#pragma unroll
        for (int m=0;m<2;m++)
#pragma unroll
            for (int j=0;j<4;j++)
#pragma unroll
                for (int s=0;s<2;s++){
                    acc[m][j] = MFMA16(ah[m][s], bh[j][s], acc[m][j], 0,0,0);
                    acc[m][j] = MFMA16(ah[m][s], bl[j][s], acc[m][j], 0,0,0);
                    acc[m][j] = MFMA16(al[m][s], bh[j][s], acc[m][j], 0,0,0);
                }
        __syncthreads();
    }

#pragma unroll
    for (int m=0;m<2;m++)
#pragma unroll
        for (int r=0;r<4;r++){
            size_t grow = (size_t)mt*128 + 32*w + 16*m + 4*g + r;
#pragma unroll
            for (int j=0;j<4;j++)
                out[grow*EE + nt*64 + 16*j + ln] = acc[m][j][r];
        }
}

// ---------------------------------------------------------------------------
extern "C" void kernel_launch(void* const* d_in, const int* in_sizes, int n_in,
                              void* d_out, int out_size, void* d_ws, size_t ws_size,
                              hipStream_t stream)
{
    (void)in_sizes; (void)n_in; (void)out_size; (void)ws_size;
    const float* x     = (const float*)d_in[0];
    const float* ve    = (const float*)d_in[1];
    const float* cosb  = (const float*)d_in[2];
    const float* sinb  = (const float*)d_in[3];
    const float* Wq    = (const float*)d_in[4];
    const float* Wk    = (const float*)d_in[5];
    const float* Wv    = (const float*)d_in[6];
    const float* Wp    = (const float*)d_in[7];
    const float* Wg    = (const float*)d_in[8];
    const int*   amask = (const int*)d_in[9];
    const int*   lw    = (const int*)d_in[10];

    char* ws = (char*)d_ws;
    ushort* qhb = (ushort*)(ws);                      // 8 MB  q hi [b*16+h][s][64]
    ushort* qlb = (ushort*)(ws + ( 8u<<20));          // 8 MB  q lo
    ushort* khb = (ushort*)(ws + (16u<<20));          // 2 MB  k hi [b*4+kvh][s][64]
    ushort* klb = (ushort*)(ws + (18u<<20));          // 2 MB  k lo
    ushort* vhT = (ushort*)(ws + (20u<<20));          // 2 MB  v^T hi [b*4+kvh][64][s]
    ushort* vlT = (ushort*)(ws + (22u<<20));          // 2 MB  v^T lo
    ushort* yhb = (ushort*)(ws + (24u<<20));          // 8 MB  y hi [4096][1024]
    ushort* ylb = (ushort*)(ws + (32u<<20));          // 8 MB  y lo (total 40 MB)

    qk_kernel<<<dim3(20,32), 256, 0, stream>>>(x, Wq, Wk, cosb, sinb,
                                               qhb, qlb, khb, klb);
    v_kernel <<<dim3(4,32),  256, 0, stream>>>(x, ve, Wv, Wg, vhT, vlT);
    attn_kernel<<<dim3(32,32), 256, 0, stream>>>(qhb, qlb, khb, klb, vhT, vlT,
                                                 amask, lw, yhb, ylb);
    proj_kernel<<<dim3(16,32), 256, 0, stream>>>(yhb, ylb, Wp, (float*)d_out);
}

// Round 7
// 296.030 us; speedup vs baseline: 8.3260x; 1.4342x over previous
//
#include <hip/hip_runtime.h>
#include <hip/hip_bf16.h>

// PicoLlmAttention: split-bf16 (hi+lo) MFMA pipeline, fp32-accurate everywhere.
// B=2, S=2048, E=1024, H=16, KV=4, D=64, window read from device.
#define SS 2048
#define EE 1024
#define RMS_EPS 1.1920929e-07f

typedef short v8s __attribute__((ext_vector_type(8)));   // 8 bf16 (4 VGPR)
typedef float v4f __attribute__((ext_vector_type(4)));   // MFMA acc

#define MFMA16 __builtin_amdgcn_mfma_f32_16x16x32_bf16

__device__ __forceinline__ ushort f2bf(float f){
    union { __hip_bfloat16 b; ushort u; } c; c.b = __float2bfloat16(f); return c.u;
}
__device__ __forceinline__ float bf2f(ushort u){
    union { uint u; float f; } c; c.u = ((uint)u) << 16; return c.f;
}
// split 8 consecutive fp32 into hi/lo bf16 packs (hi+lo ~ 16+ mantissa bits)
__device__ __forceinline__ void split8(const float* p, uint4& H, uint4& L){
    float4 a = *(const float4*)p, b = *(const float4*)(p+4);
    float v[8] = {a.x,a.y,a.z,a.w,b.x,b.y,b.z,b.w};
    ushort hs[8], ls[8];
#pragma unroll
    for (int e=0;e<8;e++){
        ushort h = f2bf(v[e]);
        hs[e] = h;
        ls[e] = f2bf(v[e] - bf2f(h));
    }
    H = *(uint4*)hs; L = *(uint4*)ls;
}

// ---------------------------------------------------------------------------
// QKV projection: split-bf16 MFMA GEMM 128(M s) x 64(N d, one head).
// nt<16: Q (RoPE+RMS), nt in [16,20): K (RoPE+RMS), nt in [20,24): V (gate+ve).
// grid (24, 32), block 256 (4 waves; wave w owns 32 M-rows)
// ---------------------------------------------------------------------------
__global__ __launch_bounds__(256)
void qkv_kernel(const float* __restrict__ x, const float* __restrict__ ve,
                const float* __restrict__ Wq, const float* __restrict__ Wk,
                const float* __restrict__ Wv, const float* __restrict__ Wg,
                const float* __restrict__ cosb, const float* __restrict__ sinb,
                ushort* __restrict__ qhb, ushort* __restrict__ qlb,
                ushort* __restrict__ khb, ushort* __restrict__ klb,
                ushort* __restrict__ vhT, ushort* __restrict__ vlT)
{
    __shared__ ushort Axh[128*64];   // 16 KB
    __shared__ ushort Axl[128*64];   // 16 KB
    __shared__ ushort Bwh[64*64];    //  8 KB
    __shared__ ushort Bwl[64*64];    //  8 KB
    const int t = threadIdx.x;
    const int lane = t & 63, w = t >> 6;
    const int g = lane >> 4, ln = lane & 15;
    const int nt = blockIdx.x, mt = blockIdx.y;
    const float* W;
    if (nt < 16)      W = Wq + (size_t)nt*64*EE;
    else if (nt < 20) W = Wk + (size_t)(nt-16)*64*EE;
    else              W = Wv + (size_t)(nt-20)*64*EE;
    const v4f vzero = {0.f,0.f,0.f,0.f};
    v4f acc[2][4];
#pragma unroll
    for (int m=0;m<2;m++)
#pragma unroll
        for (int j=0;j<4;j++) acc[m][j] = vzero;

    const int sr = t>>3, sc = t&7;
    for (int kt = 0; kt < EE; kt += 64){
#pragma unroll
        for (int p2=0;p2<4;p2++){
            int rr = sr + 32*p2;
            uint4 H,L; split8(x + (size_t)(mt*128+rr)*EE + kt + sc*8, H, L);
            int off = rr*64 + ((sc ^ (rr&7))<<3);
            *(uint4*)&Axh[off] = H; *(uint4*)&Axl[off] = L;
        }
#pragma unroll
        for (int p2=0;p2<2;p2++){
            int rr = sr + 32*p2;
            uint4 H,L; split8(W + (size_t)rr*EE + kt + sc*8, H, L);
            int off = rr*64 + ((sc ^ (rr&7))<<3);
            *(uint4*)&Bwh[off] = H; *(uint4*)&Bwl[off] = L;
        }
        __syncthreads();
        v8s ah[2][2], al[2][2], bh[4][2], bl[4][2];
#pragma unroll
        for (int m=0;m<2;m++){
            int row = 32*w + 16*m + ln;
#pragma unroll
            for (int s=0;s<2;s++){
                int off = row*64 + (((4*s+g) ^ (row&7))<<3);
                ah[m][s] = *(v8s*)&Axh[off];
                al[m][s] = *(v8s*)&Axl[off];
            }
        }
#pragma unroll
        for (int j=0;j<4;j++){
            int row = 16*j + ln;
#pragma unroll
            for (int s=0;s<2;s++){
                int off = row*64 + (((4*s+g) ^ (row&7))<<3);
                bh[j][s] = *(v8s*)&Bwh[off];
                bl[j][s] = *(v8s*)&Bwl[off];
            }
        }
#pragma unroll
        for (int m=0;m<2;m++)
#pragma unroll
            for (int j=0;j<4;j++)
#pragma unroll
                for (int s=0;s<2;s++){
                    acc[m][j] = MFMA16(ah[m][s], bh[j][s], acc[m][j], 0,0,0);
                    acc[m][j] = MFMA16(ah[m][s], bl[j][s], acc[m][j], 0,0,0);
                    acc[m][j] = MFMA16(al[m][s], bh[j][s], acc[m][j], 0,0,0);
                }
        __syncthreads();
    }

    // epilogue: lane holds C cols d = {ln,16+ln,32+ln,48+ln}, rows s = 32w+16m+4g+r
#pragma unroll
    for (int m=0;m<2;m++){
#pragma unroll
        for (int r=0;r<4;r++){
            int srow = mt*128 + 32*w + 16*m + 4*g + r;
            int bb  = srow >> 11;
            int ss_ = srow & 2047;
            float v0 = acc[m][0][r], v1 = acc[m][1][r];
            float v2 = acc[m][2][r], v3 = acc[m][3][r];
            if (nt < 20){
                // RoPE + RMSNorm*1.2, split-bf16 store
                float c0 = cosb[ss_*32 + ln],      s0 = sinb[ss_*32 + ln];
                float c1 = cosb[ss_*32 + 16 + ln], s1 = sinb[ss_*32 + 16 + ln];
                float lo0 =  v0*c0 + v2*s0, hi0 = -v0*s0 + v2*c0;  // d=ln    / 32+ln
                float lo1 =  v1*c1 + v3*s1, hi1 = -v1*s1 + v3*c1;  // d=16+ln / 48+ln
                float ssq = lo0*lo0 + hi0*hi0 + lo1*lo1 + hi1*hi1;
                ssq += __shfl_xor(ssq, 1); ssq += __shfl_xor(ssq, 2);
                ssq += __shfl_xor(ssq, 4); ssq += __shfl_xor(ssq, 8);
                float rs = rsqrtf(ssq*(1.f/64.f) + RMS_EPS) * 1.2f;
                size_t base = (nt < 16) ? ((size_t)(bb*16 + nt)*SS + ss_)*64
                                        : ((size_t)(bb*4 + (nt-16))*SS + ss_)*64;
                ushort* dh = (nt < 16) ? (qhb + base) : (khb + base);
                ushort* dl = (nt < 16) ? (qlb + base) : (klb + base);
                float o0 = lo0*rs, o1 = lo1*rs, o2 = hi0*rs, o3 = hi1*rs;
                ushort h0 = f2bf(o0), h1 = f2bf(o1), h2 = f2bf(o2), h3 = f2bf(o3);
                dh[ln]    = h0; dl[ln]    = f2bf(o0 - bf2f(h0));
                dh[16+ln] = h1; dl[16+ln] = f2bf(o1 - bf2f(h1));
                dh[32+ln] = h2; dl[32+ln] = f2bf(o2 - bf2f(h2));
                dh[48+ln] = h3; dl[48+ln] = f2bf(o3 - bf2f(h3));
            } else {
                // V head: out = acc + gate*ve, split-bf16 transposed store
                int head = nt - 20;
                float gsum = 0.f;
                const float* xr = x + (size_t)srow * EE;
#pragma unroll
                for (int c = 0; c < 12; c++) gsum += xr[c] * Wg[head*12 + c];
                float gate = 3.f / (1.f + __expf(-gsum));
                const float* ver = ve + (size_t)srow*256 + head*64;
                size_t vbase = ((size_t)(bb*4 + head)*64)*SS + ss_;
                float dv[4] = {v0, v1, v2, v3};
#pragma unroll
                for (int j=0;j<4;j++){
                    int d = 16*j + ln;
                    float ov = dv[j] + gate*ver[d];
                    ushort hh = f2bf(ov);
                    vhT[vbase + (size_t)d*SS] = hh;
                    vlT[vbase + (size_t)d*SS] = f2bf(ov - bf2f(hh));
                }
            }
        }
    }
}

// ---------------------------------------------------------------------------
// Flash attention, split-bf16 QK^T and PV (3-term each); P stays in registers.
// grid (32 qtiles, 32 b*h), block 256 (4 waves; wave w owns q rows 16w..16w+15)
// ---------------------------------------------------------------------------
__global__ __launch_bounds__(256)
void attn_kernel(const ushort* __restrict__ qhb, const ushort* __restrict__ qlb,
                 const ushort* __restrict__ khb, const ushort* __restrict__ klb,
                 const ushort* __restrict__ vhT, const ushort* __restrict__ vlT,
                 const int* __restrict__ amask, const int* __restrict__ lwp,
                 ushort* __restrict__ yhb, ushort* __restrict__ ylb)
{
    __shared__ ushort SMEM[24576];   // Qh|Ql|Kh|Kl|Vh|Vl (4096 ush each); epi: Ot f32
    __shared__ float mbias[64];
    ushort* Qh = SMEM;
    ushort* Ql = SMEM + 4096;
    ushort* Kh = SMEM + 8192;
    ushort* Kl = SMEM + 12288;
    ushort* Vh = SMEM + 16384;
    ushort* Vl = SMEM + 20480;
    const int t = threadIdx.x, lane = t & 63, w = t >> 6;
    const int g = lane >> 4, ln = lane & 15;
    const int qt = blockIdx.x, bh = blockIdx.y;
    const int b = bh >> 4, h = bh & 15, kvh = h >> 2;
    const int LW = lwp[0];
    const int q0 = qt*64;
    const ushort* Qhp = qhb + ((size_t)(b*16+h)*SS + q0)*64;
    const ushort* Qlp = qlb + ((size_t)(b*16+h)*SS + q0)*64;
    const ushort* Khp = khb + ((size_t)(b*4+kvh)*SS)*64;
    const ushort* Klp = klb + ((size_t)(b*4+kvh)*SS)*64;
    const ushort* Vhp = vhT + (size_t)(b*4+kvh)*64*SS;
    const ushort* Vlp = vlT + (size_t)(b*4+kvh)*64*SS;

    const int sr = t>>3, sc = t&7;
#pragma unroll
    for (int p2=0;p2<2;p2++){
        int rr = sr + 32*p2;
        int off = rr*64 + ((sc ^ (rr&7))<<3);
        *(uint4*)&Qh[off] = *(const uint4*)(Qhp + (size_t)rr*64 + sc*8);
        *(uint4*)&Ql[off] = *(const uint4*)(Qlp + (size_t)rr*64 + sc*8);
    }
    __syncthreads();
    v8s qfh[2], qfl[2];
    {
        int row = 16*w + ln;
#pragma unroll
        for (int s=0;s<2;s++){
            int off = row*64 + (((4*s+g) ^ (row&7))<<3);
            qfh[s] = *(v8s*)&Qh[off];
            qfl[s] = *(v8s*)&Ql[off];
        }
    }
    const int qg = q0 + 16*w + ln;
    const int keyk = (ln&3) ^ ((ln>>2)<<1);
    float m_r = -1e30f, l_r = 0.f;
    const v4f vzero = {0.f,0.f,0.f,0.f};
    v4f o[4];
#pragma unroll
    for (int dt=0;dt<4;dt++) o[dt] = vzero;

    int lo = q0 - LW + 1; if (lo < 0) lo = 0;
    for (int kt = lo>>6; kt <= qt; kt++){
        int k0 = kt*64;
        __syncthreads();
#pragma unroll
        for (int p2=0;p2<2;p2++){
            int rr = sr + 32*p2;
            int kkey = (rr&3) ^ (((rr>>3)&3)<<1);
            int koff = rr*64 + ((sc ^ kkey)<<3);
            *(uint4*)&Kh[koff] = *(const uint4*)(Khp + (size_t)(k0+rr)*64 + sc*8);
            *(uint4*)&Kl[koff] = *(const uint4*)(Klp + (size_t)(k0+rr)*64 + sc*8);
            int voff = rr*64 + ((sc ^ (rr&7))<<3);
            *(uint4*)&Vh[voff] = *(const uint4*)(Vhp + (size_t)rr*SS + k0 + sc*8);
            *(uint4*)&Vl[voff] = *(const uint4*)(Vlp + (size_t)rr*SS + k0 + sc*8);
        }
        if (t < 64) mbias[t] = amask[(b<<11) + k0 + t] ? 0.f : -3.0e38f;
        __syncthreads();

        // S^T = K . Q^T (3-term split), permuted k-rows
        float p[4][4];
#pragma unroll
        for (int tau=0;tau<4;tau++){
            v4f sa = vzero;
            int krow = 32*(tau&1) + 8*(ln>>2) + 4*(tau>>1) + (ln&3);
#pragma unroll
            for (int s=0;s<2;s++){
                int off = krow*64 + (((4*s+g) ^ keyk)<<3);
                v8s afh = *(v8s*)&Kh[off];
                v8s afl = *(v8s*)&Kl[off];
                sa = MFMA16(afh, qfh[s], sa, 0,0,0);
                sa = MFMA16(afh, qfl[s], sa, 0,0,0);
                sa = MFMA16(afl, qfh[s], sa, 0,0,0);
            }
#pragma unroll
            for (int r=0;r<4;r++) p[tau][r] = sa[r];
        }

        // mask + online softmax (per-lane: col q = ln is this lane's q)
        float pmax = -3.0e38f;
#pragma unroll
        for (int tau=0;tau<4;tau++)
#pragma unroll
            for (int r=0;r<4;r++){
                int kk  = 32*(tau&1) + 8*g + 4*(tau>>1) + r;
                int kgl = k0 + kk;
                float scv = p[tau][r]*0.125f + mbias[kk];
                bool ok = (kgl <= qg) && (qg - kgl < LW);
                scv = ok ? scv : -3.0e38f;
                p[tau][r] = scv;
                pmax = fmaxf(pmax, scv);
            }
        pmax = fmaxf(pmax, __shfl_xor(pmax,16));
        pmax = fmaxf(pmax, __shfl_xor(pmax,32));
        float mnew = fmaxf(m_r, pmax);
        float al = __expf(m_r - mnew);
        float ls = 0.f;
#pragma unroll
        for (int tau=0;tau<4;tau++)
#pragma unroll
            for (int r=0;r<4;r++){
                float e = __expf(p[tau][r] - mnew);
                p[tau][r] = e; ls += e;
            }
        ls += __shfl_xor(ls,16); ls += __shfl_xor(ls,32);
        m_r = mnew; l_r = l_r*al + ls;

        // pack split P (per-lane): B-frag elem e of K-step s <- p[2*(e>>2)+s][e&3]
        v8s pbh[2], pbl[2];
#pragma unroll
        for (int s=0;s<2;s++){
            v8s ph, pl;
#pragma unroll
            for (int e=0;e<8;e++){
                float val = p[2*(e>>2)+s][e&3];
                ushort hh = f2bf(val);
                ph[e] = (short)hh;
                pl[e] = (short)f2bf(val - bf2f(hh));
            }
            pbh[s]=ph; pbl[s]=pl;
        }
        // O^T += V^T . P^T (3-term split)
#pragma unroll
        for (int dt=0;dt<4;dt++){
            o[dt] = o[dt]*al;
            int drow = 16*dt + ln;
#pragma unroll
            for (int s=0;s<2;s++){
                int off = drow*64 + (((4*s+g) ^ (ln&7))<<3);
                v8s vfh = *(v8s*)&Vh[off];
                v8s vfl = *(v8s*)&Vl[off];
                o[dt] = MFMA16(vfh, pbh[s], o[dt], 0,0,0);
                o[dt] = MFMA16(vfh, pbl[s], o[dt], 0,0,0);
                o[dt] = MFMA16(vfl, pbh[s], o[dt], 0,0,0);
            }
        }
    }

    // epilogue: O^T -> LDS transpose (stride 68) -> coalesced split-bf16 y rows
    __syncthreads();
    float inv = (l_r > 0.f) ? (1.0f / l_r) : 0.f;
    float* Ot = (float*)SMEM;
#pragma unroll
    for (int dt=0;dt<4;dt++)
#pragma unroll
        for (int r=0;r<4;r++){
            int d = 16*dt + 4*g + r;
            Ot[d*68 + 16*w + ln] = o[dt][r]*inv;
        }
    __syncthreads();
    {
        int q = t>>2, dp = t&3;
        ushort th[16], tl[16];
#pragma unroll
        for (int i=0;i<16;i++){
            float val = Ot[(dp*16+i)*68 + q];
            ushort hh = f2bf(val);
            th[i] = hh;
            tl[i] = f2bf(val - bf2f(hh));
        }
        size_t doff = (size_t)(b*SS + q0 + q)*EE + h*64 + dp*16;
        *(uint4*)(yhb + doff)     = *(uint4*)&th[0];
        *(uint4*)(yhb + doff + 8) = *(uint4*)&th[8];
        *(uint4*)(ylb + doff)     = *(uint4*)&tl[0];
        *(uint4*)(ylb + doff + 8) = *(uint4*)&tl[8];
    }
}

// ---------------------------------------------------------------------------
// Output projection: split-bf16 MFMA GEMM (y hi/lo from ws, Wp split in staging),
// out fp32.  grid (16, 32), block 256
// ---------------------------------------------------------------------------
__global__ __launch_bounds__(256)
void proj_kernel(const ushort* __restrict__ yhb, const ushort* __restrict__ ylb,
                 const float* __restrict__ Wp, float* __restrict__ out)
{
    __shared__ ushort Ayh[128*64];   // 16 KB
    __shared__ ushort Ayl[128*64];   // 16 KB
    __shared__ ushort Bh[64*64];     //  8 KB
    __shared__ ushort Bl[64*64];     //  8 KB
    const int t = threadIdx.x;
    const int lane = t & 63, w = t >> 6;
    const int g = lane >> 4, ln = lane & 15;
    const int nt = blockIdx.x, mt = blockIdx.y;
    const v4f vzero = {0.f,0.f,0.f,0.f};
    v4f acc[2][4];
#pragma unroll
    for (int m=0;m<2;m++)
#pragma unroll
        for (int j=0;j<4;j++) acc[m][j] = vzero;

    const int sr = t>>3, sc = t&7;
    for (int kt = 0; kt < EE; kt += 64){
#pragma unroll
        for (int p2=0;p2<4;p2++){
            int rr = sr + 32*p2;
            int off = rr*64 + ((sc ^ (rr&7))<<3);
            *(uint4*)&Ayh[off] = *(const uint4*)(yhb + (size_t)(mt*128+rr)*EE + kt + sc*8);
            *(uint4*)&Ayl[off] = *(const uint4*)(ylb + (size_t)(mt*128+rr)*EE + kt + sc*8);
        }
#pragma unroll
        for (int p2=0;p2<2;p2++){
            int rr = sr + 32*p2;
            uint4 H,L; split8(Wp + (size_t)(nt*64+rr)*EE + kt + sc*8, H, L);
            int off = rr*64 + ((sc ^ (rr&7))<<3);
            *(uint4*)&Bh[off] = H; *(uint4*)&Bl[off] = L;
        }
        __syncthreads();
        v8s ah[2][2], al[2][2], bh[4][2], bl[4][2];
#pragma unroll
        for (int m=0;m<2;m++){
            int row = 32*w + 16*m + ln;
#pragma unroll
            for (int s=0;s<2;s++){
                int off = row*64 + (((4*s+g) ^ (row&7))<<3);
                ah[m][s] = *(v8s*)&Ayh[off];
                al[m][s] = *(v8s*)&Ayl[off];
            }
        }
#pragma unroll
        for (int j=0;j<4;j++){
            int row = 16*j + ln;
#pragma unroll
            for (int s=0;s<2;s++){
                int off = row*64 + (((4*s+g) ^ (row&7))<<3);
                bh[j][s] = *(v8s*)&Bh[off];
                bl[j][s] = *(v8s*)&Bl[off];
            }
        }
#pragma unroll
        for (int m=0;m<2;m++)
#pragma unroll
            for (int j=0;j<4;j++)
#pragma unroll
                for (int s=0;s<2;s++){
                    acc[m][j] = MFMA16(ah[m][s], bh[j][s], acc[m][j], 0,0,0);
                    acc[m][j] = MFMA16(ah[m][s], bl[j][s], acc[m][j], 0,0,0);
                    acc[m][j] = MFMA16(al[m][s], bh[j][s], acc[m][j], 0,0,0);
                }
        __syncthreads();
    }

#pragma unroll
    for (int m=0;m<2;m++)
#pragma unroll
        for (int r=0;r<4;r++){
            size_t grow = (size_t)mt*128 + 32*w + 16*m + 4*g + r;
#pragma unroll
            for (int j=0;j<4;j++)
                out[grow*EE + nt*64 + 16*j + ln] = acc[m][j][r];
        }
}

// ---------------------------------------------------------------------------
extern "C" void kernel_launch(void* const* d_in, const int* in_sizes, int n_in,
                              void* d_out, int out_size, void* d_ws, size_t ws_size,
                              hipStream_t stream)
{
    (void)in_sizes; (void)n_in; (void)out_size; (void)ws_size;
    const float* x     = (const float*)d_in[0];
    const float* ve    = (const float*)d_in[1];
    const float* cosb  = (const float*)d_in[2];
    const float* sinb  = (const float*)d_in[3];
    const float* Wq    = (const float*)d_in[4];
    const float* Wk    = (const float*)d_in[5];
    const float* Wv    = (const float*)d_in[6];
    const float* Wp    = (const float*)d_in[7];
    const float* Wg    = (const float*)d_in[8];
    const int*   amask = (const int*)d_in[9];
    const int*   lw    = (const int*)d_in[10];

    char* ws = (char*)d_ws;
    ushort* qhb = (ushort*)(ws);                      // 8 MB  q hi [b*16+h][s][64]
    ushort* qlb = (ushort*)(ws + ( 8u<<20));          // 8 MB  q lo
    ushort* khb = (ushort*)(ws + (16u<<20));          // 2 MB  k hi [b*4+kvh][s][64]
    ushort* klb = (ushort*)(ws + (18u<<20));          // 2 MB  k lo
    ushort* vhT = (ushort*)(ws + (20u<<20));          // 2 MB  v^T hi [b*4+kvh][64][s]
    ushort* vlT = (ushort*)(ws + (22u<<20));          // 2 MB  v^T lo
    ushort* yhb = (ushort*)(ws + (24u<<20));          // 8 MB  y hi [4096][1024]
    ushort* ylb = (ushort*)(ws + (32u<<20));          // 8 MB  y lo (total 40 MB)

    qkv_kernel<<<dim3(24,32), 256, 0, stream>>>(x, ve, Wq, Wk, Wv, Wg, cosb, sinb,
                                                qhb, qlb, khb, klb, vhT, vlT);
    attn_kernel<<<dim3(32,32), 256, 0, stream>>>(qhb, qlb, khb, klb, vhT, vlT,
                                                 amask, lw, yhb, ylb);
    proj_kernel<<<dim3(16,32), 256, 0, stream>>>(yhb, ylb, Wp, (float*)d_out);
}

// Round 8
// 265.238 us; speedup vs baseline: 9.2926x; 1.1161x over previous
//
#include <hip/hip_runtime.h>
#include <hip/hip_bf16.h>

// PicoLlmAttention: split-bf16 (hi+lo) MFMA pipeline, fp32-accurate everywhere.
// Round 8: pre-split prepass (ws>=50MB path) + attn Q-direct / 32KB LDS.
// B=2, S=2048, E=1024, H=16, KV=4, D=64, window read from device.
#define SS 2048
#define EE 1024
#define RMS_EPS 1.1920929e-07f

typedef short v8s __attribute__((ext_vector_type(8)));   // 8 bf16 (4 VGPR)
typedef float v4f __attribute__((ext_vector_type(4)));   // MFMA acc

#define MFMA16 __builtin_amdgcn_mfma_f32_16x16x32_bf16

__device__ __forceinline__ ushort f2bf(float f){
    union { __hip_bfloat16 b; ushort u; } c; c.b = __float2bfloat16(f); return c.u;
}
__device__ __forceinline__ float bf2f(ushort u){
    union { uint u; float f; } c; c.u = ((uint)u) << 16; return c.f;
}
// split 8 consecutive fp32 into hi/lo bf16 packs (hi+lo ~ 16+ mantissa bits)
__device__ __forceinline__ void split8(const float* p, uint4& H, uint4& L){
    float4 a = *(const float4*)p, b = *(const float4*)(p+4);
    float v[8] = {a.x,a.y,a.z,a.w,b.x,b.y,b.z,b.w};
    ushort hs[8], ls[8];
#pragma unroll
    for (int e=0;e<8;e++){
        ushort h = f2bf(v[e]);
        hs[e] = h;
        ls[e] = f2bf(v[e] - bf2f(h));
    }
    H = *(uint4*)hs; L = *(uint4*)ls;
}

// ---------------------------------------------------------------------------
// Prepass: split fp32 -> (hi, lo) bf16 arrays.  8 elements/thread.
// ---------------------------------------------------------------------------
__global__ __launch_bounds__(256)
void split_pre(const float* __restrict__ s, ushort* __restrict__ dh,
               ushort* __restrict__ dl, int n8)
{
    int i = blockIdx.x*256 + threadIdx.x;
    if (i < n8){
        uint4 H, L;
        split8(s + (size_t)i*8, H, L);
        *(uint4*)(dh + (size_t)i*8) = H;
        *(uint4*)(dl + (size_t)i*8) = L;
    }
}

// ---------------------------------------------------------------------------
// QKV projection: split-bf16 MFMA GEMM 128(M s) x 64(N d, one head).
// nt<16: Q (RoPE+RMS), nt in [16,20): K (RoPE+RMS), nt in [20,24): V (gate+ve).
// PRE=true: stage from pre-split xh/xl and concat Wch/Wcl (row = nt*64+rr).
// grid (24, 32), block 256 (4 waves; wave w owns 32 M-rows)
// ---------------------------------------------------------------------------
template<bool PRE>
__global__ __launch_bounds__(256)
void qkv_kernel(const float* __restrict__ x, const float* __restrict__ ve,
                const float* __restrict__ Wq, const float* __restrict__ Wk,
                const float* __restrict__ Wv, const float* __restrict__ Wg,
                const ushort* __restrict__ xh, const ushort* __restrict__ xl,
                const ushort* __restrict__ Wch, const ushort* __restrict__ Wcl,
                const float* __restrict__ cosb, const float* __restrict__ sinb,
                ushort* __restrict__ qhb, ushort* __restrict__ qlb,
                ushort* __restrict__ khb, ushort* __restrict__ klb,
                ushort* __restrict__ vhT, ushort* __restrict__ vlT)
{
    __shared__ ushort Axh[128*64];   // 16 KB
    __shared__ ushort Axl[128*64];   // 16 KB
    __shared__ ushort Bwh[64*64];    //  8 KB
    __shared__ ushort Bwl[64*64];    //  8 KB
    const int t = threadIdx.x;
    const int lane = t & 63, w = t >> 6;
    const int g = lane >> 4, ln = lane & 15;
    const int nt = blockIdx.x, mt = blockIdx.y;
    const float* W;
    if (nt < 16)      W = Wq + (size_t)nt*64*EE;
    else if (nt < 20) W = Wk + (size_t)(nt-16)*64*EE;
    else              W = Wv + (size_t)(nt-20)*64*EE;
    const v4f vzero = {0.f,0.f,0.f,0.f};
    v4f acc[2][4];
#pragma unroll
    for (int m=0;m<2;m++)
#pragma unroll
        for (int j=0;j<4;j++) acc[m][j] = vzero;

    const int sr = t>>3, sc = t&7;
    for (int kt = 0; kt < EE; kt += 64){
#pragma unroll
        for (int p2=0;p2<4;p2++){
            int rr = sr + 32*p2;
            int off = rr*64 + ((sc ^ (rr&7))<<3);
            if (PRE){
                *(uint4*)&Axh[off] = *(const uint4*)(xh + (size_t)(mt*128+rr)*EE + kt + sc*8);
                *(uint4*)&Axl[off] = *(const uint4*)(xl + (size_t)(mt*128+rr)*EE + kt + sc*8);
            } else {
                uint4 H,L; split8(x + (size_t)(mt*128+rr)*EE + kt + sc*8, H, L);
                *(uint4*)&Axh[off] = H; *(uint4*)&Axl[off] = L;
            }
        }
#pragma unroll
        for (int p2=0;p2<2;p2++){
            int rr = sr + 32*p2;
            int off = rr*64 + ((sc ^ (rr&7))<<3);
            if (PRE){
                *(uint4*)&Bwh[off] = *(const uint4*)(Wch + (size_t)(nt*64+rr)*EE + kt + sc*8);
                *(uint4*)&Bwl[off] = *(const uint4*)(Wcl + (size_t)(nt*64+rr)*EE + kt + sc*8);
            } else {
                uint4 H,L; split8(W + (size_t)rr*EE + kt + sc*8, H, L);
                *(uint4*)&Bwh[off] = H; *(uint4*)&Bwl[off] = L;
            }
        }
        __syncthreads();
        v8s ah[2][2], al[2][2], bh[4][2], bl[4][2];
#pragma unroll
        for (int m=0;m<2;m++){
            int row = 32*w + 16*m + ln;
#pragma unroll
            for (int s=0;s<2;s++){
                int off = row*64 + (((4*s+g) ^ (row&7))<<3);
                ah[m][s] = *(v8s*)&Axh[off];
                al[m][s] = *(v8s*)&Axl[off];
            }
        }
#pragma unroll
        for (int j=0;j<4;j++){
            int row = 16*j + ln;
#pragma unroll
            for (int s=0;s<2;s++){
                int off = row*64 + (((4*s+g) ^ (row&7))<<3);
                bh[j][s] = *(v8s*)&Bwh[off];
                bl[j][s] = *(v8s*)&Bwl[off];
            }
        }
#pragma unroll
        for (int m=0;m<2;m++)
#pragma unroll
            for (int j=0;j<4;j++)
#pragma unroll
                for (int s=0;s<2;s++){
                    acc[m][j] = MFMA16(ah[m][s], bh[j][s], acc[m][j], 0,0,0);
                    acc[m][j] = MFMA16(ah[m][s], bl[j][s], acc[m][j], 0,0,0);
                    acc[m][j] = MFMA16(al[m][s], bh[j][s], acc[m][j], 0,0,0);
                }
        __syncthreads();
    }

    // epilogue: lane holds C cols d = {ln,16+ln,32+ln,48+ln}, rows s = 32w+16m+4g+r
#pragma unroll
    for (int m=0;m<2;m++){
#pragma unroll
        for (int r=0;r<4;r++){
            int srow = mt*128 + 32*w + 16*m + 4*g + r;
            int bb  = srow >> 11;
            int ss_ = srow & 2047;
            float v0 = acc[m][0][r], v1 = acc[m][1][r];
            float v2 = acc[m][2][r], v3 = acc[m][3][r];
            if (nt < 20){
                // RoPE + RMSNorm*1.2, split-bf16 store
                float c0 = cosb[ss_*32 + ln],      s0 = sinb[ss_*32 + ln];
                float c1 = cosb[ss_*32 + 16 + ln], s1 = sinb[ss_*32 + 16 + ln];
                float lo0 =  v0*c0 + v2*s0, hi0 = -v0*s0 + v2*c0;  // d=ln    / 32+ln
                float lo1 =  v1*c1 + v3*s1, hi1 = -v1*s1 + v3*c1;  // d=16+ln / 48+ln
                float ssq = lo0*lo0 + hi0*hi0 + lo1*lo1 + hi1*hi1;
                ssq += __shfl_xor(ssq, 1); ssq += __shfl_xor(ssq, 2);
                ssq += __shfl_xor(ssq, 4); ssq += __shfl_xor(ssq, 8);
                float rs = rsqrtf(ssq*(1.f/64.f) + RMS_EPS) * 1.2f;
                size_t base = (nt < 16) ? ((size_t)(bb*16 + nt)*SS + ss_)*64
                                        : ((size_t)(bb*4 + (nt-16))*SS + ss_)*64;
                ushort* dh = (nt < 16) ? (qhb + base) : (khb + base);
                ushort* dl = (nt < 16) ? (qlb + base) : (klb + base);
                float o0 = lo0*rs, o1 = lo1*rs, o2 = hi0*rs, o3 = hi1*rs;
                ushort h0 = f2bf(o0), h1 = f2bf(o1), h2 = f2bf(o2), h3 = f2bf(o3);
                dh[ln]    = h0; dl[ln]    = f2bf(o0 - bf2f(h0));
                dh[16+ln] = h1; dl[16+ln] = f2bf(o1 - bf2f(h1));
                dh[32+ln] = h2; dl[32+ln] = f2bf(o2 - bf2f(h2));
                dh[48+ln] = h3; dl[48+ln] = f2bf(o3 - bf2f(h3));
            } else {
                // V head: out = acc + gate*ve, split-bf16 transposed store
                int head = nt - 20;
                float gsum = 0.f;
                const float* xr = x + (size_t)srow * EE;
#pragma unroll
                for (int c = 0; c < 12; c++) gsum += xr[c] * Wg[head*12 + c];
                float gate = 3.f / (1.f + __expf(-gsum));
                const float* ver = ve + (size_t)srow*256 + head*64;
                size_t vbase = ((size_t)(bb*4 + head)*64)*SS + ss_;
                float dv[4] = {v0, v1, v2, v3};
#pragma unroll
                for (int j=0;j<4;j++){
                    int d = 16*j + ln;
                    float ov = dv[j] + gate*ver[d];
                    ushort hh = f2bf(ov);
                    vhT[vbase + (size_t)d*SS] = hh;
                    vlT[vbase + (size_t)d*SS] = f2bf(ov - bf2f(hh));
                }
            }
        }
    }
}

// ---------------------------------------------------------------------------
// Flash attention, split-bf16 QK^T and PV (3-term each); P stays in registers.
// Q frags loaded directly from global (no Q LDS) -> 32KB LDS, 4 blocks/CU.
// grid (32 qtiles, 32 b*h), block 256 (4 waves; wave w owns q rows 16w..16w+15)
// ---------------------------------------------------------------------------
__global__ __launch_bounds__(256)
void attn_kernel(const ushort* __restrict__ qhb, const ushort* __restrict__ qlb,
                 const ushort* __restrict__ khb, const ushort* __restrict__ klb,
                 const ushort* __restrict__ vhT, const ushort* __restrict__ vlT,
                 const int* __restrict__ amask, const int* __restrict__ lwp,
                 ushort* __restrict__ yhb, ushort* __restrict__ ylb)
{
    __shared__ ushort SMEM[16384];   // Kh|Kl|Vh|Vl (4096 ush each); epi: Ot f32
    __shared__ float mbias[64];
    ushort* Kh = SMEM;
    ushort* Kl = SMEM + 4096;
    ushort* Vh = SMEM + 8192;
    ushort* Vl = SMEM + 12288;
    const int t = threadIdx.x, lane = t & 63, w = t >> 6;
    const int g = lane >> 4, ln = lane & 15;
    const int qt = blockIdx.x, bh = blockIdx.y;
    const int b = bh >> 4, h = bh & 15, kvh = h >> 2;
    const int LW = lwp[0];
    const int q0 = qt*64;
    const ushort* Qhp = qhb + ((size_t)(b*16+h)*SS + q0)*64;
    const ushort* Qlp = qlb + ((size_t)(b*16+h)*SS + q0)*64;
    const ushort* Khp = khb + ((size_t)(b*4+kvh)*SS)*64;
    const ushort* Klp = klb + ((size_t)(b*4+kvh)*SS)*64;
    const ushort* Vhp = vhT + (size_t)(b*4+kvh)*64*SS;
    const ushort* Vlp = vlT + (size_t)(b*4+kvh)*64*SS;

    // Q frags direct from global: row = 16w+ln, 8 consecutive d at (4s+g)*8
    v8s qfh[2], qfl[2];
    {
        int row = 16*w + ln;
#pragma unroll
        for (int s=0;s<2;s++){
            qfh[s] = *(const v8s*)(Qhp + (size_t)row*64 + (4*s+g)*8);
            qfl[s] = *(const v8s*)(Qlp + (size_t)row*64 + (4*s+g)*8);
        }
    }
    const int qg = q0 + 16*w + ln;
    const int keyk = (ln&3) ^ ((ln>>2)<<1);
    float m_r = -1e30f, l_r = 0.f;
    const v4f vzero = {0.f,0.f,0.f,0.f};
    v4f o[4];
#pragma unroll
    for (int dt=0;dt<4;dt++) o[dt] = vzero;

    const int sr = t>>3, sc = t&7;
    int lo = q0 - LW + 1; if (lo < 0) lo = 0;
    for (int kt = lo>>6; kt <= qt; kt++){
        int k0 = kt*64;
        __syncthreads();
#pragma unroll
        for (int p2=0;p2<2;p2++){
            int rr = sr + 32*p2;
            int kkey = (rr&3) ^ (((rr>>3)&3)<<1);
            int koff = rr*64 + ((sc ^ kkey)<<3);
            *(uint4*)&Kh[koff] = *(const uint4*)(Khp + (size_t)(k0+rr)*64 + sc*8);
            *(uint4*)&Kl[koff] = *(const uint4*)(Klp + (size_t)(k0+rr)*64 + sc*8);
            int voff = rr*64 + ((sc ^ (rr&7))<<3);
            *(uint4*)&Vh[voff] = *(const uint4*)(Vhp + (size_t)rr*SS + k0 + sc*8);
            *(uint4*)&Vl[voff] = *(const uint4*)(Vlp + (size_t)rr*SS + k0 + sc*8);
        }
        if (t < 64) mbias[t] = amask[(b<<11) + k0 + t] ? 0.f : -3.0e38f;
        __syncthreads();

        // S^T = K . Q^T (3-term split), permuted k-rows
        float p[4][4];
#pragma unroll
        for (int tau=0;tau<4;tau++){
            v4f sa = vzero;
            int krow = 32*(tau&1) + 8*(ln>>2) + 4*(tau>>1) + (ln&3);
#pragma unroll
            for (int s=0;s<2;s++){
                int off = krow*64 + (((4*s+g) ^ keyk)<<3);
                v8s afh = *(v8s*)&Kh[off];
                v8s afl = *(v8s*)&Kl[off];
                sa = MFMA16(afh, qfh[s], sa, 0,0,0);
                sa = MFMA16(afh, qfl[s], sa, 0,0,0);
                sa = MFMA16(afl, qfh[s], sa, 0,0,0);
            }
#pragma unroll
            for (int r=0;r<4;r++) p[tau][r] = sa[r];
        }

        // mask + online softmax (per-lane: col q = ln is this lane's q)
        float pmax = -3.0e38f;
#pragma unroll
        for (int tau=0;tau<4;tau++)
#pragma unroll
            for (int r=0;r<4;r++){
                int kk  = 32*(tau&1) + 8*g + 4*(tau>>1) + r;
                int kgl = k0 + kk;
                float scv = p[tau][r]*0.125f + mbias[kk];
                bool ok = (kgl <= qg) && (qg - kgl < LW);
                scv = ok ? scv : -3.0e38f;
                p[tau][r] = scv;
                pmax = fmaxf(pmax, scv);
            }
        pmax = fmaxf(pmax, __shfl_xor(pmax,16));
        pmax = fmaxf(pmax, __shfl_xor(pmax,32));
        float mnew = fmaxf(m_r, pmax);
        float al = __expf(m_r - mnew);
        float ls = 0.f;
#pragma unroll
        for (int tau=0;tau<4;tau++)
#pragma unroll
            for (int r=0;r<4;r++){
                float e = __expf(p[tau][r] - mnew);
                p[tau][r] = e; ls += e;
            }
        ls += __shfl_xor(ls,16); ls += __shfl_xor(ls,32);
        m_r = mnew; l_r = l_r*al + ls;

        // pack split P (per-lane): B-frag elem e of K-step s <- p[2*(e>>2)+s][e&3]
        v8s pbh[2], pbl[2];
#pragma unroll
        for (int s=0;s<2;s++){
            v8s ph, pl;
#pragma unroll
            for (int e=0;e<8;e++){
                float val = p[2*(e>>2)+s][e&3];
                ushort hh = f2bf(val);
                ph[e] = (short)hh;
                pl[e] = (short)f2bf(val - bf2f(hh));
            }
            pbh[s]=ph; pbl[s]=pl;
        }
        // O^T += V^T . P^T (3-term split)
#pragma unroll
        for (int dt=0;dt<4;dt++){
            o[dt] = o[dt]*al;
            int drow = 16*dt + ln;
#pragma unroll
            for (int s=0;s<2;s++){
                int off = drow*64 + (((4*s+g) ^ (ln&7))<<3);
                v8s vfh = *(v8s*)&Vh[off];
                v8s vfl = *(v8s*)&Vl[off];
                o[dt] = MFMA16(vfh, pbh[s], o[dt], 0,0,0);
                o[dt] = MFMA16(vfh, pbl[s], o[dt], 0,0,0);
                o[dt] = MFMA16(vfl, pbh[s], o[dt], 0,0,0);
            }
        }
    }

    // epilogue: O^T -> LDS transpose (stride 68) -> coalesced split-bf16 y rows
    __syncthreads();
    float inv = (l_r > 0.f) ? (1.0f / l_r) : 0.f;
    float* Ot = (float*)SMEM;
#pragma unroll
    for (int dt=0;dt<4;dt++)
#pragma unroll
        for (int r=0;r<4;r++){
            int d = 16*dt + 4*g + r;
            Ot[d*68 + 16*w + ln] = o[dt][r]*inv;
        }
    __syncthreads();
    {
        int q = t>>2, dp = t&3;
        ushort th[16], tl[16];
#pragma unroll
        for (int i=0;i<16;i++){
            float val = Ot[(dp*16+i)*68 + q];
            ushort hh = f2bf(val);
            th[i] = hh;
            tl[i] = f2bf(val - bf2f(hh));
        }
        size_t doff = (size_t)(b*SS + q0 + q)*EE + h*64 + dp*16;
        *(uint4*)(yhb + doff)     = *(uint4*)&th[0];
        *(uint4*)(yhb + doff + 8) = *(uint4*)&th[8];
        *(uint4*)(ylb + doff)     = *(uint4*)&tl[0];
        *(uint4*)(ylb + doff + 8) = *(uint4*)&tl[8];
    }
}

// ---------------------------------------------------------------------------
// Output projection: split-bf16 MFMA GEMM, out fp32.  grid (16, 32), block 256
// PRE=true: B staged from pre-split Wph/Wpl.
// ---------------------------------------------------------------------------
template<bool PRE>
__global__ __launch_bounds__(256)
void proj_kernel(const ushort* __restrict__ yhb, const ushort* __restrict__ ylb,
                 const float* __restrict__ Wp, const ushort* __restrict__ Wph,
                 const ushort* __restrict__ Wpl, float* __restrict__ out)
{
    __shared__ ushort Ayh[128*64];   // 16 KB
    __shared__ ushort Ayl[128*64];   // 16 KB
    __shared__ ushort Bh[64*64];     //  8 KB
    __shared__ ushort Bl[64*64];     //  8 KB
    const int t = threadIdx.x;
    const int lane = t & 63, w = t >> 6;
    const int g = lane >> 4, ln = lane & 15;
    const int nt = blockIdx.x, mt = blockIdx.y;
    const v4f vzero = {0.f,0.f,0.f,0.f};
    v4f acc[2][4];
#pragma unroll
    for (int m=0;m<2;m++)
#pragma unroll
        for (int j=0;j<4;j++) acc[m][j] = vzero;

    const int sr = t>>3, sc = t&7;
    for (int kt = 0; kt < EE; kt += 64){
#pragma unroll
        for (int p2=0;p2<4;p2++){
            int rr = sr + 32*p2;
            int off = rr*64 + ((sc ^ (rr&7))<<3);
            *(uint4*)&Ayh[off] = *(const uint4*)(yhb + (size_t)(mt*128+rr)*EE + kt + sc*8);
            *(uint4*)&Ayl[off] = *(const uint4*)(ylb + (size_t)(mt*128+rr)*EE + kt + sc*8);
        }
#pragma unroll
        for (int p2=0;p2<2;p2++){
            int rr = sr + 32*p2;
            int off = rr*64 + ((sc ^ (rr&7))<<3);
            if (PRE){
                *(uint4*)&Bh[off] = *(const uint4*)(Wph + (size_t)(nt*64+rr)*EE + kt + sc*8);
                *(uint4*)&Bl[off] = *(const uint4*)(Wpl + (size_t)(nt*64+rr)*EE + kt + sc*8);
            } else {
                uint4 H,L; split8(Wp + (size_t)(nt*64+rr)*EE + kt + sc*8, H, L);
                *(uint4*)&Bh[off] = H; *(uint4*)&Bl[off] = L;
            }
        }
        __syncthreads();
        v8s ah[2][2], al[2][2], bh[4][2], bl[4][2];
#pragma unroll
        for (int m=0;m<2;m++){
            int row = 32*w + 16*m + ln;
#pragma unroll
            for (int s=0;s<2;s++){
                int off = row*64 + (((4*s+g) ^ (row&7))<<3);
                ah[m][s] = *(v8s*)&Ayh[off];
                al[m][s] = *(v8s*)&Ayl[off];
            }
        }
#pragma unroll
        for (int j=0;j<4;j++){
            int row = 16*j + ln;
#pragma unroll
            for (int s=0;s<2;s++){
                int off = row*64 + (((4*s+g) ^ (row&7))<<3);
                bh[j][s] = *(v8s*)&Bh[off];
                bl[j][s] = *(v8s*)&Bl[off];
            }
        }
#pragma unroll
        for (int m=0;m<2;m++)
#pragma unroll
            for (int j=0;j<4;j++)
#pragma unroll
                for (int s=0;s<2;s++){
                    acc[m][j] = MFMA16(ah[m][s], bh[j][s], acc[m][j], 0,0,0);
                    acc[m][j] = MFMA16(ah[m][s], bl[j][s], acc[m][j], 0,0,0);
                    acc[m][j] = MFMA16(al[m][s], bh[j][s], acc[m][j], 0,0,0);
                }
        __syncthreads();
    }

#pragma unroll
    for (int m=0;m<2;m++)
#pragma unroll
        for (int r=0;r<4;r++){
            size_t grow = (size_t)mt*128 + 32*w + 16*m + 4*g + r;
#pragma unroll
            for (int j=0;j<4;j++)
                out[grow*EE + nt*64 + 16*j + ln] = acc[m][j][r];
        }
}

// ---------------------------------------------------------------------------
extern "C" void kernel_launch(void* const* d_in, const int* in_sizes, int n_in,
                              void* d_out, int out_size, void* d_ws, size_t ws_size,
                              hipStream_t stream)
{
    (void)in_sizes; (void)n_in; (void)out_size;
    const float* x     = (const float*)d_in[0];
    const float* ve    = (const float*)d_in[1];
    const float* cosb  = (const float*)d_in[2];
    const float* sinb  = (const float*)d_in[3];
    const float* Wq    = (const float*)d_in[4];
    const float* Wk    = (const float*)d_in[5];
    const float* Wv    = (const float*)d_in[6];
    const float* Wp    = (const float*)d_in[7];
    const float* Wg    = (const float*)d_in[8];
    const int*   amask = (const int*)d_in[9];
    const int*   lw    = (const int*)d_in[10];
    float* out = (float*)d_out;
    char* ws = (char*)d_ws;

    if (ws_size >= (size_t)(50u<<20)){
        // ---- pre-split path (50 MB) ----
        ushort* xh  = (ushort*)(ws);                 // 8 MB  x hi   -> later y hi
        ushort* xl  = (ushort*)(ws + ( 8u<<20));     // 8 MB  x lo   -> later y lo
        ushort* Wch = (ushort*)(ws + (16u<<20));     // 3 MB  [Wq;Wk;Wv] hi
        ushort* Wcl = (ushort*)(ws + (19u<<20));     // 3 MB  [Wq;Wk;Wv] lo
        ushort* Wph = (ushort*)(ws + (22u<<20));     // 2 MB  Wp hi
        ushort* Wpl = (ushort*)(ws + (24u<<20));     // 2 MB  Wp lo
        ushort* qhb = (ushort*)(ws + (26u<<20));     // 8 MB  q hi [b*16+h][s][64]
        ushort* qlb = (ushort*)(ws + (34u<<20));     // 8 MB  q lo
        ushort* khb = (ushort*)(ws + (42u<<20));     // 2 MB  k hi [b*4+kvh][s][64]
        ushort* klb = (ushort*)(ws + (44u<<20));     // 2 MB  k lo
        ushort* vhT = (ushort*)(ws + (46u<<20));     // 2 MB  v^T hi [b*4+kvh][64][s]
        ushort* vlT = (ushort*)(ws + (48u<<20));     // 2 MB  v^T lo
        ushort* yhb = xh;                            // reuse (x dead after qkv)
        ushort* ylb = xl;

        split_pre<<<2048, 256, 0, stream>>>(x,  xh,  xl,  524288);
        split_pre<<< 512, 256, 0, stream>>>(Wq, Wch, Wcl, 131072);
        split_pre<<< 128, 256, 0, stream>>>(Wk, Wch + (size_t)1024*EE, Wcl + (size_t)1024*EE, 32768);
        split_pre<<< 128, 256, 0, stream>>>(Wv, Wch + (size_t)1280*EE, Wcl + (size_t)1280*EE, 32768);
        split_pre<<< 512, 256, 0, stream>>>(Wp, Wph, Wpl, 131072);

        qkv_kernel<true><<<dim3(24,32), 256, 0, stream>>>(x, ve, Wq, Wk, Wv, Wg,
                xh, xl, Wch, Wcl, cosb, sinb, qhb, qlb, khb, klb, vhT, vlT);
        attn_kernel<<<dim3(32,32), 256, 0, stream>>>(qhb, qlb, khb, klb, vhT, vlT,
                amask, lw, yhb, ylb);
        proj_kernel<true><<<dim3(16,32), 256, 0, stream>>>(yhb, ylb, Wp, Wph, Wpl, out);
    } else {
        // ---- fallback: split-on-the-fly path (40 MB, round-7 layout) ----
        ushort* qhb = (ushort*)(ws);                 // 8 MB
        ushort* qlb = (ushort*)(ws + ( 8u<<20));     // 8 MB
        ushort* khb = (ushort*)(ws + (16u<<20));     // 2 MB
        ushort* klb = (ushort*)(ws + (18u<<20));     // 2 MB
        ushort* vhT = (ushort*)(ws + (20u<<20));     // 2 MB
        ushort* vlT = (ushort*)(ws + (22u<<20));     // 2 MB
        ushort* yhb = (ushort*)(ws + (24u<<20));     // 8 MB
        ushort* ylb = (ushort*)(ws + (32u<<20));     // 8 MB

        qkv_kernel<false><<<dim3(24,32), 256, 0, stream>>>(x, ve, Wq, Wk, Wv, Wg,
                nullptr, nullptr, nullptr, nullptr, cosb, sinb,
                qhb, qlb, khb, klb, vhT, vlT);
        attn_kernel<<<dim3(32,32), 256, 0, stream>>>(qhb, qlb, khb, klb, vhT, vlT,
                amask, lw, yhb, ylb);
        proj_kernel<false><<<dim3(16,32), 256, 0, stream>>>(yhb, ylb, Wp, nullptr, nullptr, out);
    }
}